// Round 1
// baseline (89.556 us; speedup 1.0000x reference)
//
#include <hip/hip_runtime.h>

#define D 64
#define NN 10

typedef __bf16 bf16x8 __attribute__((ext_vector_type(8)));
typedef float f32x4 __attribute__((ext_vector_type(4)));

// ---------------------------------------------------------------------------
// Kernel 1: collapse the linear DAG into a single (M, c).
// Row-independent recurrence: M_t[i,:] = sum_{f<t} M_f[i,:] @ W[f,t].
// Block r in [0,63]: row r of M (M_0 = I).  Block 64: the bias row (c_0 = 0),
// which additionally accumulates b[f,t].
// Mc layout (d_ws): floats [0,4096) = M_9 row-major [k][j]; [4096,4160) = c_9.
// ---------------------------------------------------------------------------
__global__ __launch_bounds__(256) void wired_build(const float* __restrict__ W,
                                                   const float* __restrict__ Bv,
                                                   float* __restrict__ Mc) {
  __shared__ __align__(16) float hist[NN][D];
  __shared__ float part[4][D];
  const int r = blockIdx.x;            // 0..63 = M rows, 64 = bias row
  const int lane = threadIdx.x & 63;
  const int w = threadIdx.x >> 6;      // wave 0..3, partitions f

  if (threadIdx.x < D)
    hist[0][threadIdx.x] = (r < D && threadIdx.x == r) ? 1.0f : 0.0f;
  __syncthreads();

  for (int t = 1; t < NN; ++t) {
    float a0 = 0.f, a1 = 0.f, a2 = 0.f, a3 = 0.f;
    for (int f = w; f < t; f += 4) {
      const float* wft = W + (size_t)(f * NN + t) * D * D;
      const float4* h4 = (const float4*)hist[f];
#pragma unroll
      for (int k4 = 0; k4 < 16; ++k4) {
        float4 h = h4[k4];                       // LDS broadcast (same addr)
        a0 += h.x * wft[(k4 * 4 + 0) * D + lane]; // coalesced 256B/wave
        a1 += h.y * wft[(k4 * 4 + 1) * D + lane];
        a2 += h.z * wft[(k4 * 4 + 2) * D + lane];
        a3 += h.w * wft[(k4 * 4 + 3) * D + lane];
      }
      if (r == D) a0 += Bv[(f * NN + t) * D + lane];  // bias row picks up b[f,t]
    }
    part[w][lane] = (a0 + a1) + (a2 + a3);
    __syncthreads();
    if (w == 0)
      hist[t][lane] = part[0][lane] + part[1][lane] + part[2][lane] + part[3][lane];
    __syncthreads();
  }

  if (threadIdx.x < D)
    Mc[r * D + threadIdx.x] = hist[NN - 1][threadIdx.x];  // r==64 lands at c region
}

// ---------------------------------------------------------------------------
// Kernel 2: out = x @ M + c, memory-bound skinny GEMM via bf16 MFMA.
// B-fragments (M) are loaded once per thread and live in registers for the
// whole kernel.  A = 16-row x tile.  mfma_f32_16x16x32_bf16 layouts:
//   A[m = lane&15][k = (lane>>4)*8 + j],  B[k = (lane>>4)*8 + j][n = lane&15],
//   D[row = (lane>>4)*4 + r][col = lane&15].
// ---------------------------------------------------------------------------
__global__ __launch_bounds__(256) void wired_apply(const float* __restrict__ x,
                                                   const float* __restrict__ Mc,
                                                   float* __restrict__ out,
                                                   int nrows) {
  const int lane = threadIdx.x & 63;
  const int wave = threadIdx.x >> 6;
  const int l15 = lane & 15;
  const int quad = lane >> 4;

  // Load the whole M as 8 register-resident B fragments (one-time cost).
  bf16x8 bfrag[2][4];
#pragma unroll
  for (int kc = 0; kc < 2; ++kc) {
#pragma unroll
    for (int nc = 0; nc < 4; ++nc) {
      bf16x8 bb;
#pragma unroll
      for (int j = 0; j < 8; ++j) {
        bb[j] = (__bf16)Mc[(kc * 32 + quad * 8 + j) * D + nc * 16 + l15];
      }
      bfrag[kc][nc] = bb;
    }
  }
  float cfrag[4];
#pragma unroll
  for (int nc = 0; nc < 4; ++nc) cfrag[nc] = Mc[D * D + nc * 16 + l15];

  const int gw = blockIdx.x * 4 + wave;
  const int nw = gridDim.x * 4;
  const int ntiles = nrows >> 4;       // 16 batch rows per tile
  for (int tile = gw; tile < ntiles; tile += nw) {
    // A fragment: lane reads 8 contiguous floats of its row, twice (k and k+32)
    const float* xr = x + (size_t)(tile * 16 + l15) * D + quad * 8;
    float4 v0 = *(const float4*)(xr);
    float4 v1 = *(const float4*)(xr + 4);
    float4 v2 = *(const float4*)(xr + 32);
    float4 v3 = *(const float4*)(xr + 36);
    bf16x8 af0, af1;
    af0[0] = (__bf16)v0.x; af0[1] = (__bf16)v0.y; af0[2] = (__bf16)v0.z; af0[3] = (__bf16)v0.w;
    af0[4] = (__bf16)v1.x; af0[5] = (__bf16)v1.y; af0[6] = (__bf16)v1.z; af0[7] = (__bf16)v1.w;
    af1[0] = (__bf16)v2.x; af1[1] = (__bf16)v2.y; af1[2] = (__bf16)v2.z; af1[3] = (__bf16)v2.w;
    af1[4] = (__bf16)v3.x; af1[5] = (__bf16)v3.y; af1[6] = (__bf16)v3.z; af1[7] = (__bf16)v3.w;

#pragma unroll
    for (int nc = 0; nc < 4; ++nc) {
      f32x4 acc = {0.f, 0.f, 0.f, 0.f};
      acc = __builtin_amdgcn_mfma_f32_16x16x32_bf16(af0, bfrag[0][nc], acc, 0, 0, 0);
      acc = __builtin_amdgcn_mfma_f32_16x16x32_bf16(af1, bfrag[1][nc], acc, 0, 0, 0);
#pragma unroll
      for (int rr = 0; rr < 4; ++rr) {
        out[(size_t)(tile * 16 + quad * 4 + rr) * D + nc * 16 + l15] =
            acc[rr] + cfrag[nc];
      }
    }
  }
}

extern "C" void kernel_launch(void* const* d_in, const int* in_sizes, int n_in,
                              void* d_out, int out_size, void* d_ws, size_t ws_size,
                              hipStream_t stream) {
  const float* x = (const float*)d_in[0];   // [B, 64] fp32
  const float* W = (const float*)d_in[1];   // [10,10,64,64] fp32
  const float* Bv = (const float*)d_in[2];  // [10,10,64] fp32
  float* out = (float*)d_out;               // [B, 64] fp32
  float* Mc = (float*)d_ws;                 // 4160 floats: M (4096) + c (64)
  const int nrows = in_sizes[0] / D;        // 65536

  wired_build<<<65, 256, 0, stream>>>(W, Bv, Mc);
  wired_apply<<<256, 256, 0, stream>>>(x, Mc, out, nrows);
}